// Round 12
// baseline (267.158 us; speedup 1.0000x reference)
//
#include <hip/hip_runtime.h>
#include <cmath>

// Problem constants
#define LSIG  2097153      // signal / rfft length (= NFFT/2+1)
#define MH    2097152      // NFFT/2 (complex FFT size for packed real trick)
#define NFFTC 4194304      // 2^22
#define NT128 16384        // MH/128 = butterflies per radix-128 pass
#define O1C   1048577
#define O2C   524289
#define O3C   262145

// conv tiling: 62 o3 positions per block
#define TO3   62
#define NB3   4229         // ceil(O3C/TO3)

// Workspace byte offsets
#define A_OFF    0
#define B_OFF    16777216
#define PM_OFF   58720268
#define FEAT_OFF 58720272
// packed bf16 weights (written by kspectral's tail blocks), 16B aligned.
// COALESCED layouts: w1q = [mi(2)][quad(4)][col(16)] uint4          -> 2048 B
//                    w2q = [mt(4)][kt(5)][quad(4)][col(16)] uint4   -> 20480 B
//                    w3q = [mt(8)][kt(10)][quad(4)][col(16)] uint4  -> 81920 B
#define W2Q_OFF  50331664
#define W3Q_OFF  50352144
#define W1Q_OFF  50434064

struct SmultTab { int hidx[40]; float inv12[40]; int fk[40]; int maxe; };

typedef short short8 __attribute__((ext_vector_type(8)));
typedef float f32x4v __attribute__((ext_vector_type(4)));

union AFrag { uint4 q; short8 s; };
union BFrag { uint4 q; unsigned int u[4]; short8 s; };

__device__ __forceinline__ float lrelu(float a){ return a > 0.0f ? a : 0.2f*a; }

// HW transcendentals: v_sin_f32 / v_cos_f32 take input in REVOLUTIONS.
__device__ __forceinline__ float hsin(float rev){ return __builtin_amdgcn_sinf(rev); }
__device__ __forceinline__ float hcos(float rev){ return __builtin_amdgcn_cosf(rev); }

// bf16 pack helpers (round-nearest-even)
__device__ __forceinline__ unsigned int rbf(float f) {
  unsigned int u = __float_as_uint(f);
  u += 0x7fffu + ((u >> 16) & 1u);
  return u >> 16;
}
// HW packed convert: low16 = bf16(a), high16 = bf16(b); RNE — matches rbf.
__device__ __forceinline__ unsigned int pack_bf2(float a, float b) {
  unsigned int r;
  asm("v_cvt_pk_bf16_f32 %0, %1, %2" : "=v"(r) : "v"(a), "v"(b));
  return r;
}

// LDS XOR swizzles for kconv (dword-granular, preserve 8B alignment).
__device__ __forceinline__ int swz1(int pos, int dw) {
  return (pos*16 + dw) ^ (((pos >> 1) & 7) << 2);
}
__device__ __forceinline__ int swz2(int pos, int dw) {
  return (pos*32 + dw) ^ (((pos >> 1) & 7) << 2);
}

// FFT tile slot. BIJECTIVE: pre-swizzle sigma(q) = q ^ ((q>>4)&7) (self-inverse,
// bits 4-6 unchanged -> key recoverable), THEN rotate by 9*jj mod 128.
// Verified correct on-device (R6-R11).
__device__ __forceinline__ int slot128(int jj, int q) {
  int s = q ^ ((q >> 4) & 7);
  return jj*128 + ((s + 9*jj) & 127);
}

__device__ __forceinline__ float2 cadd(float2 a, float2 b){ return make_float2(a.x+b.x, a.y+b.y); }
__device__ __forceinline__ float2 csub(float2 a, float2 b){ return make_float2(a.x-b.x, a.y-b.y); }

// multiply by -i (FWD) or +i (INV)
template<bool FWD> __device__ __forceinline__ float2 jrot(float2 z){
  return FWD ? make_float2(z.y, -z.x) : make_float2(-z.y, z.x);
}

// natural-order radix-8 DFT butterfly
template<bool FWD> __device__ __forceinline__ void dft8(float2 v[8]) {
  const float cq = 0.70710678118654752440f;
  const float S  = FWD ? -1.0f : 1.0f;
  float2 e0 = cadd(v[0], v[4]), e1 = csub(v[0], v[4]);
  float2 e2 = cadd(v[2], v[6]), e3 = csub(v[2], v[6]);
  float2 E0 = cadd(e0, e2), E2 = csub(e0, e2);
  float2 jt = jrot<FWD>(e3);
  float2 E1 = cadd(e1, jt), E3 = csub(e1, jt);
  float2 o0 = cadd(v[1], v[5]), o1 = csub(v[1], v[5]);
  float2 o2 = cadd(v[3], v[7]), o3 = csub(v[3], v[7]);
  float2 O0 = cadd(o0, o2), O2 = csub(o0, o2);
  float2 jo = jrot<FWD>(o3);
  float2 O1 = cadd(o1, jo), O3 = csub(o1, jo);
  float2 w1 = make_float2(cq*O1.x - S*cq*O1.y, cq*O1.y + S*cq*O1.x);
  float2 w2 = jrot<FWD>(O2);
  float2 w3 = make_float2(-cq*O3.x - S*cq*O3.y, -cq*O3.y + S*cq*O3.x);
  v[0] = cadd(E0, O0); v[4] = csub(E0, O0);
  v[1] = cadd(E1, w1); v[5] = csub(E1, w1);
  v[2] = cadd(E2, w2); v[6] = csub(E2, w2);
  v[3] = cadd(E3, w3); v[7] = csub(E3, w3);
}

// Radix-128 Stockham body over one 16-butterfly LDS tile (2048 c64 = 16KB),
// 256 threads. Phase A: 16jj x 16b = 256 dft8 tasks. Phase B: full-width
// pair-split (verified exact R11): dft16 task (jj,d) split into E/O dft8
// halves on thread pair (t, t^1); DIT combine via __shfl_xor.
template<bool FWD>
__device__ __forceinline__ void fft128_body(float2* stage, int t, int jb, int Ns) {
  const float ssg = FWD ? -1.0f : 1.0f;
  const float invden = 1.0f / (float)(128 * Ns);
  // Phase A: one dft8 per thread (jj = t>>4, b = t&15), outer twiddle at read.
  {
    const int jj = t >> 4, b = t & 15;
    const int m = (jb + jj) & (Ns - 1);
    float2 v[8];
#pragma unroll
    for (int a = 0; a < 8; ++a) {
      const int r = 16*a + b;
      float2 x = stage[slot128(jj, r)];
      if (Ns > 1) {
        float rev = (float)(m * r) * invden;     // m*r < 2^21, exact
        float sn = ssg * hsin(rev), cs = hcos(rev);
        x = make_float2(x.x*cs - x.y*sn, x.x*sn + x.y*cs);
      }
      v[a] = x;
    }
    dft8<FWD>(v);
#pragma unroll
    for (int d = 0; d < 8; ++d)
      stage[slot128(jj, 16*d + b)] = v[d];
  }
  __syncthreads();
  // Phase B: jj = t>>4, d = (t>>1)&7, par = t&1 (par=0: even b -> E half;
  // par=1: odd b -> O half, applies W16^c). All 256 threads active.
  {
    const int jj = t >> 4, d = (t >> 1) & 7, par = t & 1;
    float2 h[8];
#pragma unroll
    for (int bp = 0; bp < 8; ++bp) {
      const int b = 2*bp + par;
      float2 x = stage[slot128(jj, 16*d + b)];
      float rev = (float)(b*d) * 0.0078125f;     // W128^{bd}
      float sn = ssg * hsin(rev), cs = hcos(rev);
      h[bp] = make_float2(x.x*cs - x.y*sn, x.x*sn + x.y*cs);
    }
    dft8<FWD>(h);
    if (par) {
#pragma unroll
      for (int c = 0; c < 8; ++c) {              // To[c] = O[c] * W16^c
        float rev = (float)c * 0.0625f;
        float sn = ssg * hsin(rev), cs = hcos(rev);
        h[c] = make_float2(h[c].x*cs - h[c].y*sn, h[c].x*sn + h[c].y*cs);
      }
    }
    __syncthreads();                             // all reads done before writes
    const float sgn = par ? -1.0f : 1.0f;
    const int off = d + (par << 6);              // E writes 8c+d, O writes 8c+64+d
#pragma unroll
    for (int c = 0; c < 8; ++c) {
      float px = __shfl_xor(h[c].x, 1);          // partner's E (or To)
      float py = __shfl_xor(h[c].y, 1);
      stage[slot128(jj, 8*c + off)] = make_float2(px + sgn*h[c].x, py + sgn*h[c].y);
    }
  }
  __syncthreads();
}

// Process one pre-loaded tile: regs -> LDS -> fft body -> store -> barrier.
// The NEXT tile's global loads (issued by the caller before this runs) stay
// in flight across all of it (T14 async-STAGE: reg-destined loads are not
// drained at s_barrier; the compiler waits only at first register use).
template<bool FWD, bool TRUNC>
__device__ __forceinline__ void fft_tile(float2* stage, const float4 r[4],
                                         float2* __restrict__ dst,
                                         int t, int jb, int Ns) {
#pragma unroll
  for (int c = 0; c < 4; ++c) {
    int u = t + 256*c;
    int jp = u & 7, rr = u >> 3;
    stage[slot128(2*jp,   rr)] = make_float2(r[c].x, r[c].y);
    stage[slot128(2*jp+1, rr)] = make_float2(r[c].z, r[c].w);
  }
  __syncthreads();
  fft128_body<FWD>(stage, t, jb, Ns);
  if (Ns == 1) {                                 // fully contiguous out
    for (int c = 0; c < 4; ++c) {
      int u = t + 256*c;
      int jj = u >> 6, k2 = (u & 63) * 2;
      float2 a = stage[slot128(jj, k2)], b = stage[slot128(jj, k2+1)];
      *(float4*)&dst[(jb + jj)*128 + k2] = make_float4(a.x, a.y, b.x, b.y);
    }
  } else {
    for (int c = 0; c < 4; ++c) {
      int u = t + 256*c;
      int pi = u & 7, k = u >> 3;
      int jj = 2*pi, j2 = jb + jj, m2 = j2 & (Ns - 1);
      int base = (j2 - m2)*128 + m2 + k*Ns;
      if (TRUNC && k >= 64) {
        if (k == 64 && j2 == 0) dst[base] = stage[slot128(jj, k)];
        continue;
      }
      float2 a = stage[slot128(jj, k)], b = stage[slot128(jj+1, k)];
      *(float4*)&dst[base] = make_float4(a.x, a.y, b.x, b.y);
    }
  }
  __syncthreads();                               // stage reads done before reuse
}

// Full radix-128 Stockham pass: TWO 16-butterfly tiles per block, 256 threads,
// grid = NT128/32 = 512 blocks. Both tiles' global loads are issued up front;
// tile 1's loads hide under tile 0's staging+compute+store (T14 overlap).
// TRUNC: only bins n <= 2^20 written (kconv needs LSIG real samples).
template<bool FWD, bool TRUNC>
__global__ __launch_bounds__(256) void kfft128(const float2* __restrict__ src,
                                               float2* __restrict__ dst, int Ns) {
  __shared__ float2 stage[2048];
  const int t = threadIdx.x;
  const int jb0 = blockIdx.x * 32, jb1 = jb0 + 16;
  float4 r0[4], r1[4];
#pragma unroll
  for (int c = 0; c < 4; ++c) {
    int u = t + 256*c;
    int jp = u & 7, rr = u >> 3;
    r0[c] = *(const float4*)&src[jb0 + 2*jp + rr*NT128];
  }
#pragma unroll
  for (int c = 0; c < 4; ++c) {
    int u = t + 256*c;
    int jp = u & 7, rr = u >> 3;
    r1[c] = *(const float4*)&src[jb1 + 2*jp + rr*NT128];
  }
  fft_tile<FWD, TRUNC>(stage, r0, dst, t, jb0, Ns);
  fft_tile<FWD, TRUNC>(stage, r1, dst, t, jb1, Ns);
}

// Padded-real-signal tile loader for the first forward pass (Ns=1).
__device__ __forceinline__ void zload(const float* __restrict__ zin,
                                      int jb, int t, float4 r[4]) {
#pragma unroll
  for (int c = 0; c < 4; ++c) {
    int u = t + 256*c;
    int jp = u & 7, rr = u >> 3;
    int n = jb + 2*jp + rr*NT128;                // even
    float4 q;
    if (n < 1048576)       q = *(const float4*)&((const float2*)zin)[n];
    else if (n == 1048576) q = make_float4(zin[2097152], 0.0f, 0.0f, 0.0f);
    else                   q = make_float4(0.0f, 0.0f, 0.0f, 0.0f);
    r[c] = q;
  }
}

// Fused first kernel (256 threads): blocks < 512 run the first forward
// radix-128 pass (two 16-butterfly tiles each, reg-prefetched); blocks
// 512..2559 run the prog_mean reduction + FEAT zeroing.
__global__ __launch_bounds__(256) void kfirst(
    const float* __restrict__ zin, float2* __restrict__ dst,
    const float* __restrict__ tw1, const float* __restrict__ tb1,
    const float* __restrict__ tw2, const float* __restrict__ tb2,
    const float* __restrict__ tw3, const float* __restrict__ tb3,
    const float* __restrict__ hp, float* __restrict__ pm,
    float* __restrict__ feat) {
  __shared__ float2 stage[2048];
  __shared__ float shp[8];
  __shared__ float red[256];
  const int t = threadIdx.x;
  const int bb = blockIdx.x;
  if (bb < 512) {                                // ---- FFT pass 1 (Ns=1) ----
    const int jb0 = bb * 32, jb1 = jb0 + 16;
    float4 r0[4], r1[4];
    zload(zin, jb0, t, r0);
    zload(zin, jb1, t, r1);
    fft_tile<true, false>(stage, r0, dst, t, jb0, 1);
    fft_tile<true, false>(stage, r1, dst, t, jb1, 1);
    return;
  }
  // ---- prog_mean part (2048 blocks x 256 threads) ----
  if (t < 8) { float s = 0.f; for (int j = 0; j < 4; ++j) s += hp[t*4+j]; shp[t] = s; }
  __syncthreads();
  const int gid = (bb - 512)*256 + t;            // gid < 524288
  if (gid < 32768) feat[gid] = 0.0f;             // zero FEAT accumulators
  const float Lf = 2097153.0f;
  float tnv[4], sv[4];
  int ci[4];
  float acc[4][16];
#pragma unroll
  for (int e = 0; e < 4; ++e) {
    float ti = (float)(gid + e*524288);
    float tn = ti / Lf;
    tnv[e] = tn;
    sv[e] = hsin(tn);                            // sin(2*pi*ti/L)
    ci[e] = ((int)floorf(tn * 8.0f)) & 7;
#pragma unroll
    for (int kk = 0; kk < 16; ++kk) acc[e][kk] = tb2[kk];
  }
  for (int j = 0; j < 32; ++j) {
    float a = tw1[j], b = tb1[j];
    float hj[4];
#pragma unroll
    for (int e = 0; e < 4; ++e) hj[e] = fmaxf(a*tnv[e] + b, 0.0f);
#pragma unroll
    for (int kk = 0; kk < 16; ++kk) {
      float w = tw2[j*16 + kk];
#pragma unroll
      for (int e = 0; e < 4; ++e) acc[e][kk] += hj[e]*w;
    }
  }
  float lsum = 0.0f;
  const float b31 = tb3[1];
#pragma unroll
  for (int e = 0; e < 4; ++e) {
    float mp1 = b31;
#pragma unroll
    for (int kk = 0; kk < 16; ++kk) mp1 += fmaxf(acc[e][kk], 0.0f)*tw3[kk*8+1];
    lsum += shp[ci[e]] * (1.0f + mp1*sv[e]);
  }
  if (gid == 0) {                                 // tail element i = L-1
    float ti = 2097152.0f;
    float tn = ti / Lf;
    float a1[16];
    for (int kk = 0; kk < 16; ++kk) a1[kk] = tb2[kk];
    for (int j = 0; j < 32; ++j) {
      float h = fmaxf(tw1[j]*tn + tb1[j], 0.0f);
      for (int kk = 0; kk < 16; ++kk) a1[kk] += h*tw2[j*16+kk];
    }
    float mp1 = b31;
    for (int kk = 0; kk < 16; ++kk) mp1 += fmaxf(a1[kk], 0.0f)*tw3[kk*8+1];
    float svx = hsin(tn);
    int cix = ((int)floorf(tn * 8.0f)) & 7;
    lsum += shp[cix] * (1.0f + mp1*svx);
  }
  red[t] = lsum;
  __syncthreads();
  for (int off = 128; off > 0; off >>= 1) {
    if (t < off) red[t] += red[t+off];
    __syncthreads();
  }
  if (t == 0) atomicAdd(pm, red[0]);
}

// ---- fused spectral stage helpers ----
__device__ __forceinline__ float2 xsplit(float2 zk, float2 zm, float rev) {
  float2 s  = make_float2(zk.x + zm.x, zk.y - zm.y);
  float2 dd = make_float2(zk.x - zm.x, zk.y + zm.y);
  float sn = -hsin(rev), cs = hcos(rev);
  float2 t1 = make_float2(cs*dd.x - sn*dd.y, cs*dd.y + sn*dd.x);
  return make_float2(0.5f*(s.x + t1.y), 0.5f*(s.y - t1.x));
}
__device__ __forceinline__ float2 scale_xc(float2 c, float mg, float ms) {
  if (mg > 0.0f) { float sc = ms/mg; return make_float2(c.x*sc, c.y*sc); }
  return make_float2(ms, 0.0f);
}
__device__ __forceinline__ float2 invpack(int n, float2 a, float2 b) {
  float2 s  = make_float2(a.x + b.x, a.y - b.y);
  float2 dd = make_float2(a.x - b.x, a.y + b.y);
  float rev = (float)n * (1.0f / (float)NFFTC);
  float sn = hsin(rev), cs = hcos(rev);
  float2 xo = make_float2(0.5f*(cs*dd.x - sn*dd.y), 0.5f*(cs*dd.y + sn*dd.x));
  const float sc = 1.0f / (float)MH;
  return make_float2((0.5f*s.x - xo.y)*sc, (0.5f*s.y + xo.x)*sc);
}

// Fused: rfft split + band/harmonic multipliers + magnitude smoothing +
// inverse-rfft pack, for the pair (k, MH-k) per thread (natural writes).
// Blocks >= 4096 pack the conv weights (coalesced [mt][kt][quad][col]).
__global__ __launch_bounds__(256) void kspectral(const float2* __restrict__ Z,
    float2* __restrict__ A, const float* __restrict__ bwp,
    const float* __restrict__ fwp, const float* __restrict__ pm_in, SmultTab tab,
    const float* __restrict__ c1w, const float* __restrict__ c2w,
    const float* __restrict__ c3w, unsigned short* __restrict__ w1q,
    unsigned short* __restrict__ w2q, unsigned short* __restrict__ w3q) {
  const int bb = blockIdx.x;
  const int t = threadIdx.x;
  if (bb >= 4096) {                              // folded weight packing
    int i = (bb - 4096)*256 + t;
    if (i < 1024) {
      int e = i & 7, u4 = i >> 3;
      int col = u4 & 15, quad = (u4 >> 4) & 3, mi = u4 >> 6;
      float v = (quad == 0 && e < 5) ? c1w[(mi*16 + col)*5 + e] : 0.0f;
      w1q[i] = (unsigned short)rbf(v);
    }
    if (i < 10240) {
      int e = i & 7, u4 = i >> 3;
      int col = u4 & 15, quad = (u4 >> 4) & 3, mtkt = u4 >> 6;
      int kt = mtkt % 5, mt = mtkt / 5;
      int ch = mt*16 + col, c1 = quad*8 + e;
      w2q[i] = (unsigned short)rbf(c2w[ch*160 + c1*5 + kt]);
    }
    if (i < 40960) {
      int e = i & 7, u4 = i >> 3;
      int col = u4 & 15, quad = (u4 >> 4) & 3, mtkt = u4 >> 6;
      int kt = mtkt % 10, mt = mtkt / 10;
      int ch = mt*16 + col, c2 = (kt & 1)*32 + quad*8 + e;
      w3q[i] = (unsigned short)rbf(c3w[ch*320 + c2*5 + (kt >> 1)]);
    }
    return;
  }
  __shared__ float2 Xlo[258], Xhi[258];
  __shared__ float  Mlo[258], Mhi[258];
  const int k0 = bb * 256;
  const float pm1 = 1.0f + pm_in[0] * (1.0f/8388612.0f);   // 1 + sum/(L*4)
  for (int w = t; w < 258; w += 256) {
    int k = k0 - 1 + w;                          // in [-1, 1048576]
    float2 zk = Z[k & (MH-1)];
    float2 zm = Z[(MH - k) & (MH-1)];
    {
      float2 X = xsplit(zk, zm, (float)k * (1.0f/(float)NFFTC));
      float mv = 1.0f;
      if (k <= 38050) {
        const float blo[6] = {1.0f,4.0f,8.0f,13.0f,30.0f,100.0f};
        const float bhi[6] = {4.0f,8.0f,13.0f,30.0f,100.0f,200.0f};
        const float bcn[6] = {2.5f,6.0f,10.5f,21.5f,65.0f,150.0f};
        const float bhw[6] = {0.75f,1.0f,1.25f,4.25f,17.5f,25.0f};
        float f = (float)((double)k * (22050.0/4194304.0));
#pragma unroll
        for (int b = 0; b < 6; ++b) {
          if (f >= blo[b] && f <= bhi[b]) {
            float q = (f - bcn[b]) / bhw[b];
            float mask = expf(-0.5f*q*q);
            double frd = (double)k * ((double)bcn[b] / 22050.0);
            frd -= floor(frd);
            float tm = hsin((float)frd);
            mv *= (1.0f + mask * bwp[b] * (1.0f + 0.2f*tm));
          }
        }
      }
      if (k <= tab.maxe) {
        for (int ww = 0; ww < 40; ++ww) {
          int dlt = k - tab.hidx[ww];
          if (dlt >= -15 && dlt <= 15) {
            float x = (float)dlt * 0.2f;
            float win = expf(-0.5f*x*x);
            float enh = fwp[tab.fk[ww]] * win * tab.inv12[ww] * pm1;
            mv *= (1.0f + enh);
          }
        }
      }
      X.x *= mv; X.y *= mv;
      Xlo[w] = X; Mlo[w] = sqrtf(X.x*X.x + X.y*X.y);
    }
    {
      float2 X = xsplit(zm, zk, (float)(MH - k) * (1.0f/(float)NFFTC));
      Xhi[w] = X; Mhi[w] = sqrtf(X.x*X.x + X.y*X.y);
    }
  }
  __syncthreads();
  const int k = k0 + t, w = t + 1;
  float msl = (k == 0) ? Mlo[w] : 0.7f*Mlo[w] + 0.15f*(Mlo[w-1] + Mlo[w+1]);
  float2 xl = scale_xc(Xlo[w], Mlo[w], msl);
  float msh = (k == 0) ? Mhi[w] : 0.7f*Mhi[w] + 0.15f*(Mhi[w+1] + Mhi[w-1]);
  float2 xh = scale_xc(Xhi[w], Mhi[w], msh);
  A[k] = invpack(k, xl, xh);
  if (k >= 1) A[MH - k] = invpack(MH - k, xh, xl);
  if (bb == 4095 && t == 255) {                  // self-mirror bin n = MH/2
    float2 Xm = Xlo[257]; float Mm = Mlo[257];
    float ms = 0.7f*Mm + 0.15f*(Mlo[256] + Mhi[256]);
    float2 xm = scale_xc(Xm, Mm, ms);
    A[1048576] = invpack(1048576, xm, xm);
  }
}

// Fully-MFMA conv stack (R8 M-split version — best measured).
__global__ __launch_bounds__(256, 4) void kconv(const float* __restrict__ x,
    const unsigned short* __restrict__ w1q, const unsigned short* __restrict__ w2q,
    const unsigned short* __restrict__ w3q, const float* __restrict__ c1b,
    const float* __restrict__ c2b, const float* __restrict__ c3b,
    float* __restrict__ feat) {
  __shared__ float sb[552];
  __shared__ unsigned int sh1[4352];
  __shared__ unsigned int sh2[4224];
  const int tid  = threadIdx.x;
  const int blk  = blockIdx.x;
  const int s3   = blk * TO3;
  const int lane = tid & 63;
  const int wv   = tid >> 6;
  const int col  = lane & 15;
  const int quad = lane >> 4;

  const uint4* W1 = (const uint4*)w1q;             // idx = (mi*4+quad)*16+col
  AFrag a1w[2];
#pragma unroll
  for (int mi = 0; mi < 2; ++mi)
    a1w[mi].q = W1[(mi*4 + quad)*16 + col];

  const uint4* W2 = (const uint4*)w2q;             // idx = ((mt*5+kt)*4+quad)*16+col
  const int mt2 = (wv & 1) * 2;
  const int ntb2 = (wv >> 1) * 4;
  uint4 wk2[2][5];
#pragma unroll
  for (int mi = 0; mi < 2; ++mi)
#pragma unroll
    for (int kt = 0; kt < 5; ++kt)
      wk2[mi][kt] = W2[(((mt2+mi)*5 + kt)*4 + quad)*16 + col];

  float b1r[2][4], b2r[2][4];
#pragma unroll
  for (int mi = 0; mi < 2; ++mi)
#pragma unroll
    for (int r = 0; r < 4; ++r) {
      b1r[mi][r] = c1b[mi*16 + quad*4 + r];
      b2r[mi][r] = c2b[(mt2+mi)*16 + quad*4 + r];
    }

  {
    const int pb = 8*s3 - 14;
    for (int idx = tid; idx < 552; idx += 256) {
      int p = pb + idx;
      sb[idx] = (idx < 517 && p >= 0 && p < LSIG) ? x[p] : 0.0f;
    }
    if (tid < 128) sh2[4096 + tid] = 0u;
  }
  __syncthreads();

  // conv1 MFMA: 2 M-tiles x 17 N-tiles (positions 0..271, masked past 257).
  {
    const int a1 = 4*s3 - 6;
    for (int nt = wv; nt < 17; nt += 4) {
      const int n = nt*16 + col;
      BFrag bf;
      if (quad == 0) {
        const float* ps = &sb[2*n];
        bf.u[0] = pack_bf2(ps[0], ps[1]);
        bf.u[1] = pack_bf2(ps[2], ps[3]);
        bf.u[2] = pack_bf2(ps[4], ps[5]);
        bf.u[3] = pack_bf2(ps[6], ps[7]);
      } else {
        bf.u[0] = 0u; bf.u[1] = 0u; bf.u[2] = 0u; bf.u[3] = 0u;
      }
      f32x4v acc[2];
      acc[0] = (f32x4v){b1r[0][0], b1r[0][1], b1r[0][2], b1r[0][3]};
      acc[1] = (f32x4v){b1r[1][0], b1r[1][1], b1r[1][2], b1r[1][3]};
      acc[0] = __builtin_amdgcn_mfma_f32_16x16x32_bf16(a1w[0].s, bf.s, acc[0], 0, 0, 0);
      acc[1] = __builtin_amdgcn_mfma_f32_16x16x32_bf16(a1w[1].s, bf.s, acc[1], 0, 0, 0);
      const int o1 = a1 + n;
      const bool ok = (n <= 257) && (o1 >= 0) && (o1 < O1C);
#pragma unroll
      for (int mi = 0; mi < 2; ++mi) {
        float v0 = ok ? lrelu(acc[mi][0]) : 0.0f;
        float v1 = ok ? lrelu(acc[mi][1]) : 0.0f;
        float v2 = ok ? lrelu(acc[mi][2]) : 0.0f;
        float v3 = ok ? lrelu(acc[mi][3]) : 0.0f;
        uint2 pk; pk.x = pack_bf2(v0, v1); pk.y = pack_bf2(v2, v3);
        *(uint2*)&sh1[swz1(n, mi*8 + quad*2)] = pk;
      }
    }
  }
  __syncthreads();

  // conv2 MFMA: 2 mt x 4 nt, K-tiles 0..4 (tap-major); B-frag = one b128.
  f32x4v acc2[2][4];
#pragma unroll
  for (int mi = 0; mi < 2; ++mi)
#pragma unroll
    for (int nt = 0; nt < 4; ++nt)
      acc2[mi][nt] = (f32x4v){b2r[mi][0], b2r[mi][1], b2r[mi][2], b2r[mi][3]};
#pragma unroll
  for (int kt = 0; kt < 5; ++kt) {
#pragma unroll
    for (int nt = 0; nt < 4; ++nt) {
      const int n = (ntb2 + nt)*16 + col;
      const int row = 2*n + kt;
      BFrag bf;
      bf.q = *(const uint4*)&sh1[swz1(row, quad*4)];
      AFrag a0, a1; a0.q = wk2[0][kt]; a1.q = wk2[1][kt];
      acc2[0][nt] = __builtin_amdgcn_mfma_f32_16x16x32_bf16(a0.s, bf.s, acc2[0][nt], 0, 0, 0);
      acc2[1][nt] = __builtin_amdgcn_mfma_f32_16x16x32_bf16(a1.s, bf.s, acc2[1][nt], 0, 0, 0);
    }
  }

  // conv2 epilogue: lrelu + bounds -> h2t bf16 (b64 channel-quad writes)
  {
    const int a2 = 2*s3 - 2;
#pragma unroll
    for (int nt = 0; nt < 4; ++nt) {
      const int p = (ntb2 + nt)*16 + col;
      const int o2 = a2 + p;
      const bool ok = (o2 >= 0) && (o2 < O2C);
#pragma unroll
      for (int mi = 0; mi < 2; ++mi) {
        float v0 = ok ? lrelu(acc2[mi][nt][0]) : 0.0f;
        float v1 = ok ? lrelu(acc2[mi][nt][1]) : 0.0f;
        float v2 = ok ? lrelu(acc2[mi][nt][2]) : 0.0f;
        float v3 = ok ? lrelu(acc2[mi][nt][3]) : 0.0f;
        const int dwb = (mt2+mi)*8 + quad*2;
        uint2 pk; pk.x = pack_bf2(v0, v1); pk.y = pack_bf2(v2, v3);
        *(uint2*)&sh2[swz2(p, dwb)] = pk;
      }
    }
  }
  __syncthreads();

  // conv3 MFMA: TWO passes of 1 M-tile x 4 N-tiles x 10 K-tiles (tap-major).
  {
    const uint4* W3 = (const uint4*)w3q;           // idx = ((mt*10+kt)*4+quad)*16+col
    const int slot = (blk & 255) * 128;
#pragma unroll
    for (int pass = 0; pass < 2; ++pass) {
      const int mt = wv + 4*pass;
      uint4 wk3[10];
#pragma unroll
      for (int kt = 0; kt < 10; ++kt)
        wk3[kt] = W3[((mt*10 + kt)*4 + quad)*16 + col];
      float b3r[4];
#pragma unroll
      for (int r = 0; r < 4; ++r) b3r[r] = c3b[mt*16 + quad*4 + r];
      f32x4v acc3[4];
#pragma unroll
      for (int nt = 0; nt < 4; ++nt)
        acc3[nt] = (f32x4v){b3r[0], b3r[1], b3r[2], b3r[3]};
#pragma unroll
      for (int kt = 0; kt < 10; ++kt) {
        const int tap = kt >> 1;
        const int hh  = (kt & 1) * 16;
#pragma unroll
        for (int nt = 0; nt < 4; ++nt) {
          const int n = nt*16 + col;
          const int row = 2*n + tap;
          BFrag bf;
          bf.q = *(const uint4*)&sh2[swz2(row, hh + quad*4)];
          AFrag a; a.q = wk3[kt];
          acc3[nt] = __builtin_amdgcn_mfma_f32_16x16x32_bf16(a.s, bf.s, acc3[nt], 0, 0, 0);
        }
      }
#pragma unroll
      for (int r = 0; r < 4; ++r) {
        const int ch = mt*16 + quad*4 + r;
        float v = 0.0f;
#pragma unroll
        for (int nt = 0; nt < 4; ++nt) {
          const int n = nt*16 + col;
          const bool ok = (n < TO3) && (s3 + n < O3C);
          if (ok) v += lrelu(acc3[nt][r]);
        }
        v += __shfl_xor(v, 1);
        v += __shfl_xor(v, 2);
        v += __shfl_xor(v, 4);
        v += __shfl_xor(v, 8);
        if (col == 0) atomicAdd(&feat[slot + ch], v);
      }
    }
  }
}

// final mean + 2-layer MLP -> one f32 scalar
__global__ __launch_bounds__(256) void kfinal(const float* __restrict__ feat,
    const float* __restrict__ mw1, const float* __restrict__ mb1,
    const float* __restrict__ mw2, const float* __restrict__ mb2,
    float* __restrict__ out) {
  __shared__ float sfeat[128];
  __shared__ float red[256];
  const int tid = threadIdx.x;
  if (tid < 128) {
    float s = 0.0f;
    for (int sl = 0; sl < 256; ++sl) s += feat[sl*128 + tid];
    sfeat[tid] = s / 262145.0f;
  }
  __syncthreads();
  float y = mb1[tid];
  for (int i = 0; i < 128; ++i) y += sfeat[i] * mw1[i*256 + tid];
  y = y > 0.0f ? y : 0.2f*y;
  red[tid] = y * mw2[tid];
  __syncthreads();
  for (int off = 128; off > 0; off >>= 1) {
    if (tid < off) red[tid] += red[tid+off];
    __syncthreads();
  }
  if (tid == 0) out[0] = red[0] + mb2[0];
}

extern "C" void kernel_launch(void* const* d_in, const int* in_sizes, int n_in,
                              void* d_out, int out_size, void* d_ws, size_t ws_size,
                              hipStream_t stream) {
  (void)in_sizes; (void)n_in; (void)out_size; (void)ws_size;
  const float* z   = (const float*)d_in[0];
  const float* bw  = (const float*)d_in[2];
  const float* fw  = (const float*)d_in[3];
  const float* hp  = (const float*)d_in[4];
  const float* tw1 = (const float*)d_in[5];
  const float* tb1 = (const float*)d_in[6];
  const float* tw2 = (const float*)d_in[7];
  const float* tb2 = (const float*)d_in[8];
  const float* tw3 = (const float*)d_in[9];
  const float* tb3 = (const float*)d_in[10];
  const float* c1w = (const float*)d_in[11];
  const float* c1b = (const float*)d_in[12];
  const float* c2w = (const float*)d_in[13];
  const float* c2b = (const float*)d_in[14];
  const float* c3w = (const float*)d_in[15];
  const float* c3b = (const float*)d_in[16];
  const float* mw1 = (const float*)d_in[17];
  const float* mb1 = (const float*)d_in[18];
  const float* mw2 = (const float*)d_in[19];
  const float* mb2 = (const float*)d_in[20];

  char* wsb = (char*)d_ws;
  float2* A    = (float2*)(wsb + A_OFF);
  float2* B    = (float2*)(wsb + B_OFF);
  float*  PM   = (float*)(wsb + PM_OFF);
  float*  FEAT = (float*)(wsb + FEAT_OFF);
  unsigned short* W1Q = (unsigned short*)(wsb + W1Q_OFF);
  unsigned short* W2Q = (unsigned short*)(wsb + W2Q_OFF);
  unsigned short* W3Q = (unsigned short*)(wsb + W3Q_OFF);

  // static harmonic-window table
  SmultTab tab;
  {
    const double spec[8] = {7.83, 528.0, 396.0, 2.5, 14.1, 432.0, 6.0, 30.0};
    int n = 0, maxe = 0;
    for (int kk = 0; kk < 8; ++kk)
      for (int m = 1; m <= 5; ++m) {
        double hf = spec[kk] * (double)m;
        if (hf >= 11025.0) continue;
        int hidx = (int)std::floor(hf * (4194304.0/22050.0) + 0.5);
        tab.hidx[n]  = hidx;
        tab.inv12[n] = (float)(1.0/std::pow((double)m, 1.2));
        tab.fk[n]    = kk;
        if (hidx + 15 > maxe) maxe = hidx + 15;
        ++n;
      }
    tab.maxe = maxe;  // n == 40
  }

  (void)hipMemsetAsync(wsb + PM_OFF, 0, 4, stream);   // PM only

  // fused: forward FFT pass 1 (blocks 0..511, 2 tiles each) + prog_mean
  kfirst<<<2560,256,0,stream>>>(z, A, tw1,tb1,tw2,tb2,tw3,tb3,hp, PM, FEAT);

  // forward cfft: radix 128 x 128 x 128 -> natural-order spectrum in A
  kfft128<true,false><<<512,256,0,stream>>>(A, B, 128);
  kfft128<true,false><<<512,256,0,stream>>>(B, A, 16384);

  // fused spectral stage (natural writes) + weight packing
  kspectral<<<4256,256,0,stream>>>(A, B, bw, fw, PM, tab, c1w, c2w, c3w, W1Q, W2Q, W3Q);

  // inverse cfft: radix 128 x 128 x 128 (last pass truncated to needed bins)
  kfft128<false,false><<<512,256,0,stream>>>(B, A, 1);
  kfft128<false,false><<<512,256,0,stream>>>(A, B, 128);
  kfft128<false,true ><<<512,256,0,stream>>>(B, A, 16384);

  kconv<<<NB3,256,0,stream>>>((const float*)A, W1Q, W2Q, W3Q, c1b, c2b, c3b, FEAT);
  kfinal<<<1,256,0,stream>>>(FEAT, mw1, mb1, mw2, mb2, (float*)d_out);
}

// Round 13
// 253.261 us; speedup vs baseline: 1.0549x; 1.0549x over previous
//
#include <hip/hip_runtime.h>
#include <cmath>

// Problem constants
#define LSIG  2097153      // signal / rfft length (= NFFT/2+1)
#define MH    2097152      // NFFT/2 (complex FFT size for packed real trick)
#define NFFTC 4194304      // 2^22
#define NT128 16384        // MH/128 = butterflies per radix-128 pass
#define O1C   1048577
#define O2C   524289
#define O3C   262145

// conv tiling: 62 o3 positions per block
#define TO3   62
#define NB3   4229         // ceil(O3C/TO3)

// Workspace byte offsets
#define A_OFF    0
#define B_OFF    16777216
#define PM_OFF   58720268
#define FEAT_OFF 58720272
// packed bf16 weights (written by kspectral's tail blocks), 16B aligned.
// COALESCED layouts: w1q = [mi(2)][quad(4)][col(16)] uint4          -> 2048 B
//                    w2q = [mt(4)][kt(5)][quad(4)][col(16)] uint4   -> 20480 B
//                    w3q = [mt(8)][kt(10)][quad(4)][col(16)] uint4  -> 81920 B
#define W2Q_OFF  50331664
#define W3Q_OFF  50352144
#define W1Q_OFF  50434064

struct SmultTab { int hidx[40]; float inv12[40]; int fk[40]; int maxe; };

typedef short short8 __attribute__((ext_vector_type(8)));
typedef float f32x4v __attribute__((ext_vector_type(4)));

union AFrag { uint4 q; short8 s; };
union BFrag { uint4 q; unsigned int u[4]; short8 s; };

__device__ __forceinline__ float lrelu(float a){ return a > 0.0f ? a : 0.2f*a; }

// HW transcendentals: v_sin_f32 / v_cos_f32 take input in REVOLUTIONS.
__device__ __forceinline__ float hsin(float rev){ return __builtin_amdgcn_sinf(rev); }
__device__ __forceinline__ float hcos(float rev){ return __builtin_amdgcn_cosf(rev); }

// bf16 pack helpers (round-nearest-even)
__device__ __forceinline__ unsigned int rbf(float f) {
  unsigned int u = __float_as_uint(f);
  u += 0x7fffu + ((u >> 16) & 1u);
  return u >> 16;
}
// HW packed convert: low16 = bf16(a), high16 = bf16(b); RNE — matches rbf.
__device__ __forceinline__ unsigned int pack_bf2(float a, float b) {
  unsigned int r;
  asm("v_cvt_pk_bf16_f32 %0, %1, %2" : "=v"(r) : "v"(a), "v"(b));
  return r;
}

// LDS XOR swizzles for kconv (dword-granular, preserve 8B alignment).
__device__ __forceinline__ int swz1(int pos, int dw) {
  return (pos*16 + dw) ^ (((pos >> 1) & 7) << 2);
}
__device__ __forceinline__ int swz2(int pos, int dw) {
  return (pos*32 + dw) ^ (((pos >> 1) & 7) << 2);
}

// FFT tile slot. BIJECTIVE: pre-swizzle sigma(q) = q ^ ((q>>4)&7) (self-inverse,
// bits 4-6 unchanged -> key recoverable), THEN rotate by 9*jj mod 128.
// sigma injects the dft16 lane index d into the bank index. Verified (R6/R7).
__device__ __forceinline__ int slot128(int jj, int q) {
  int s = q ^ ((q >> 4) & 7);
  return jj*128 + ((s + 9*jj) & 127);
}

__device__ __forceinline__ float2 cadd(float2 a, float2 b){ return make_float2(a.x+b.x, a.y+b.y); }
__device__ __forceinline__ float2 csub(float2 a, float2 b){ return make_float2(a.x-b.x, a.y-b.y); }

// multiply by -i (FWD) or +i (INV)
template<bool FWD> __device__ __forceinline__ float2 jrot(float2 z){
  return FWD ? make_float2(z.y, -z.x) : make_float2(-z.y, z.x);
}

// natural-order radix-8 DFT butterfly
template<bool FWD> __device__ __forceinline__ void dft8(float2 v[8]) {
  const float cq = 0.70710678118654752440f;
  const float S  = FWD ? -1.0f : 1.0f;
  float2 e0 = cadd(v[0], v[4]), e1 = csub(v[0], v[4]);
  float2 e2 = cadd(v[2], v[6]), e3 = csub(v[2], v[6]);
  float2 E0 = cadd(e0, e2), E2 = csub(e0, e2);
  float2 jt = jrot<FWD>(e3);
  float2 E1 = cadd(e1, jt), E3 = csub(e1, jt);
  float2 o0 = cadd(v[1], v[5]), o1 = csub(v[1], v[5]);
  float2 o2 = cadd(v[3], v[7]), o3 = csub(v[3], v[7]);
  float2 O0 = cadd(o0, o2), O2 = csub(o0, o2);
  float2 jo = jrot<FWD>(o3);
  float2 O1 = cadd(o1, jo), O3 = csub(o1, jo);
  float2 w1 = make_float2(cq*O1.x - S*cq*O1.y, cq*O1.y + S*cq*O1.x);
  float2 w2 = jrot<FWD>(O2);
  float2 w3 = make_float2(-cq*O3.x - S*cq*O3.y, -cq*O3.y + S*cq*O3.x);
  v[0] = cadd(E0, O0); v[4] = csub(E0, O0);
  v[1] = cadd(E1, w1); v[5] = csub(E1, w1);
  v[2] = cadd(E2, w2); v[6] = csub(E2, w2);
  v[3] = cadd(E3, w3); v[7] = csub(E3, w3);
}

// Radix-128 Stockham body over one 32-butterfly LDS tile (4096 c64 = 32KB).
template<bool FWD>
__device__ __forceinline__ void fft128_body(float2* stage, int t, int jb, int Ns) {
  const float ssg = FWD ? -1.0f : 1.0f;
  const float invden = 1.0f / (float)(128 * Ns);
  // Phase A: one dft8 per thread (jj = t>>4, b = t&15), outer twiddle at read.
  {
    const int jj = t >> 4, b = t & 15;
    const int m = (jb + jj) & (Ns - 1);
    float2 v[8];
#pragma unroll
    for (int a = 0; a < 8; ++a) {
      const int r = 16*a + b;
      float2 x = stage[slot128(jj, r)];
      if (Ns > 1) {
        float rev = (float)(m * r) * invden;     // m*r < 2^21, exact
        float sn = ssg * hsin(rev), cs = hcos(rev);
        x = make_float2(x.x*cs - x.y*sn, x.x*sn + x.y*cs);
      }
      v[a] = x;
    }
    dft8<FWD>(v);
#pragma unroll
    for (int d = 0; d < 8; ++d)
      stage[slot128(jj, 16*d + b)] = v[d];
  }
  __syncthreads();
  // Phase B: one dft16 per thread (t<256: jj = t>>3, d = t&7).
  {
    float2 y[16];
    const int jj = (t & 255) >> 3, d = t & 7;
    if (t < 256) {
#pragma unroll
      for (int b = 0; b < 16; ++b) {
        float2 x = stage[slot128(jj, 16*d + b)];
        float rev = (float)(b*d) * 0.0078125f;   // W128^{bd}
        float sn = ssg * hsin(rev), cs = hcos(rev);
        y[b] = make_float2(x.x*cs - x.y*sn, x.x*sn + x.y*cs);
      }
    }
    __syncthreads();                             // all reads done before writes
    if (t < 256) {
      float2 E[8], O[8];
#pragma unroll
      for (int b = 0; b < 8; ++b) { E[b] = y[2*b]; O[b] = y[2*b+1]; }
      dft8<FWD>(E);
      dft8<FWD>(O);
#pragma unroll
      for (int c = 0; c < 8; ++c) {              // Y[c]=E+T O, Y[c+8]=E-T O
        float rev = (float)c * 0.0625f;          // W16^c
        float sn = ssg * hsin(rev), cs = hcos(rev);
        float2 To = make_float2(O[c].x*cs - O[c].y*sn, O[c].x*sn + O[c].y*cs);
        stage[slot128(jj, 8*c + d)]      = cadd(E[c], To);
        stage[slot128(jj, 8*c + 64 + d)] = csub(E[c], To);
      }
    }
  }
  __syncthreads();
}

// Full radix-128 Stockham pass: 32 consecutive butterflies/block, 512 threads.
// float4 global I/O: pairs (jj=2*jp, jj+1) are contiguous in memory for every
// Ns (block j-range [jb, jb+32) always lies in one 128-aligned group, so
// (j2-m2) is run-constant and m2 advances by 1 with jj). 16B/lane coalescing.
// TRUNC (last inverse pass): only bins n <= 2^20 written (kconv needs LSIG).
template<bool FWD, bool TRUNC>
__global__ __launch_bounds__(512) void kfft128(const float2* __restrict__ src,
                                               float2* __restrict__ dst, int Ns) {
  __shared__ float2 stage[4096];
  const int t = threadIdx.x;
  const int jb = blockIdx.x * 32;                // grid = NT128/32 = 512 blocks
  for (int c = 0; c < 4; ++c) {                  // coalesced float4 load
    int u = t + 512*c;                           // u in [0, 2048)
    int jp = u & 15, rr = u >> 4;
    float4 q = *(const float4*)&src[jb + 2*jp + rr*NT128];
    stage[slot128(2*jp,   rr)] = make_float2(q.x, q.y);
    stage[slot128(2*jp+1, rr)] = make_float2(q.z, q.w);
  }
  __syncthreads();
  fft128_body<FWD>(stage, t, jb, Ns);
  if (Ns == 1) {                                 // fully contiguous out
    for (int c = 0; c < 4; ++c) {
      int u = t + 512*c;
      int jj = u >> 6, k2 = (u & 63) * 2;
      float2 a = stage[slot128(jj, k2)], b = stage[slot128(jj, k2+1)];
      *(float4*)&dst[(jb + jj)*128 + k2] = make_float4(a.x, a.y, b.x, b.y);
    }
  } else {
    for (int c = 0; c < 4; ++c) {
      int u = t + 512*c;
      int pi = u & 15, k = u >> 4;
      int jj = 2*pi, j2 = jb + jj, m2 = j2 & (Ns - 1);
      int base = (j2 - m2)*128 + m2 + k*Ns;
      if (TRUNC && k >= 64) {
        if (k == 64 && j2 == 0) dst[base] = stage[slot128(jj, k)];
        continue;
      }
      float2 a = stage[slot128(jj, k)], b = stage[slot128(jj+1, k)];
      *(float4*)&dst[base] = make_float4(a.x, a.y, b.x, b.y);
    }
  }
}

// Fused first kernel: blocks < 512 run the first forward radix-128 pass
// (float4 z-reads, zero-half skipped); blocks 512..1535 run the prog_mean
// reduction + FEAT zeroing. Prog weights are read DIRECTLY from global with
// wave-uniform indices -> compiler scalarizes to s_load (SGPR operands, K$).
__global__ __launch_bounds__(512) void kfirst(
    const float* __restrict__ zin, float2* __restrict__ dst,
    const float* __restrict__ tw1, const float* __restrict__ tb1,
    const float* __restrict__ tw2, const float* __restrict__ tb2,
    const float* __restrict__ tw3, const float* __restrict__ tb3,
    const float* __restrict__ hp, float* __restrict__ pm,
    float* __restrict__ feat) {
  __shared__ float2 stage[4096];
  __shared__ float shp[8];
  __shared__ float red[512];
  const int t = threadIdx.x;
  const int bb = blockIdx.x;
  if (bb < 512) {                                // ---- FFT pass 1 (Ns=1) ----
    const int jb = bb * 32;
    for (int c = 0; c < 4; ++c) {
      int u = t + 512*c;
      int jp = u & 15, rr = u >> 4;
      int n = jb + 2*jp + rr*NT128;              // even
      float2 a0, a1;
      if (n < 1048576) {                         // n even -> n+1 also in range
        float4 q = *(const float4*)&((const float2*)zin)[n];
        a0 = make_float2(q.x, q.y); a1 = make_float2(q.z, q.w);
      } else if (n == 1048576) {
        a0 = make_float2(zin[2097152], 0.0f); a1 = make_float2(0.0f, 0.0f);
      } else {
        a0 = make_float2(0.0f, 0.0f); a1 = a0;
      }
      stage[slot128(2*jp,   rr)] = a0;
      stage[slot128(2*jp+1, rr)] = a1;
    }
    __syncthreads();
    fft128_body<true>(stage, t, jb, 1);
    for (int c = 0; c < 4; ++c) {                // contiguous float4 out
      int u = t + 512*c;
      int jj = u >> 6, k2 = (u & 63) * 2;
      float2 a = stage[slot128(jj, k2)], b = stage[slot128(jj, k2+1)];
      *(float4*)&dst[(jb + jj)*128 + k2] = make_float4(a.x, a.y, b.x, b.y);
    }
    return;
  }
  // ---- prog_mean part (1024 blocks x 512 threads), scalarized weights ----
  if (t < 8) { float s = 0.f; for (int j = 0; j < 4; ++j) s += hp[t*4+j]; shp[t] = s; }
  __syncthreads();
  const int gid = (bb - 512)*512 + t;            // gid < 524288
  if (gid < 32768) feat[gid] = 0.0f;             // zero FEAT accumulators
  const float Lf = 2097153.0f;
  float tnv[4], sv[4];
  int ci[4];
  float acc[4][16];
#pragma unroll
  for (int e = 0; e < 4; ++e) {
    float ti = (float)(gid + e*524288);
    float tn = ti / Lf;
    tnv[e] = tn;
    sv[e] = hsin(tn);                            // sin(2*pi*ti/L)
    ci[e] = ((int)floorf(tn * 8.0f)) & 7;
#pragma unroll
    for (int kk = 0; kk < 16; ++kk) acc[e][kk] = tb2[kk];
  }
  for (int j = 0; j < 32; ++j) {
    float a = tw1[j], b = tb1[j];                // uniform -> s_load
    float hj[4];
#pragma unroll
    for (int e = 0; e < 4; ++e) hj[e] = fmaxf(a*tnv[e] + b, 0.0f);
#pragma unroll
    for (int kk = 0; kk < 16; ++kk) {
      float w = tw2[j*16 + kk];                  // uniform -> s_load
#pragma unroll
      for (int e = 0; e < 4; ++e) acc[e][kk] += hj[e]*w;
    }
  }
  float lsum = 0.0f;
  const float b31 = tb3[1];
#pragma unroll
  for (int e = 0; e < 4; ++e) {
    float mp1 = b31;
#pragma unroll
    for (int kk = 0; kk < 16; ++kk) mp1 += fmaxf(acc[e][kk], 0.0f)*tw3[kk*8+1];
    lsum += shp[ci[e]] * (1.0f + mp1*sv[e]);
  }
  if (gid == 0) {                                 // tail element i = L-1
    float ti = 2097152.0f;
    float tn = ti / Lf;
    float a1[16];
    for (int kk = 0; kk < 16; ++kk) a1[kk] = tb2[kk];
    for (int j = 0; j < 32; ++j) {
      float h = fmaxf(tw1[j]*tn + tb1[j], 0.0f);
      for (int kk = 0; kk < 16; ++kk) a1[kk] += h*tw2[j*16+kk];
    }
    float mp1 = b31;
    for (int kk = 0; kk < 16; ++kk) mp1 += fmaxf(a1[kk], 0.0f)*tw3[kk*8+1];
    float svx = hsin(tn);
    int cix = ((int)floorf(tn * 8.0f)) & 7;
    lsum += shp[cix] * (1.0f + mp1*svx);
  }
  red[t] = lsum;
  __syncthreads();
  for (int off = 256; off > 0; off >>= 1) {
    if (t < off) red[t] += red[t+off];
    __syncthreads();
  }
  if (t == 0) atomicAdd(pm, red[0]);
}

// ---- fused spectral stage helpers ----
__device__ __forceinline__ float2 xsplit(float2 zk, float2 zm, float rev) {
  float2 s  = make_float2(zk.x + zm.x, zk.y - zm.y);
  float2 dd = make_float2(zk.x - zm.x, zk.y + zm.y);
  float sn = -hsin(rev), cs = hcos(rev);
  float2 t1 = make_float2(cs*dd.x - sn*dd.y, cs*dd.y + sn*dd.x);
  return make_float2(0.5f*(s.x + t1.y), 0.5f*(s.y - t1.x));
}
__device__ __forceinline__ float2 scale_xc(float2 c, float mg, float ms) {
  if (mg > 0.0f) { float sc = ms/mg; return make_float2(c.x*sc, c.y*sc); }
  return make_float2(ms, 0.0f);
}
__device__ __forceinline__ float2 invpack(int n, float2 a, float2 b) {
  float2 s  = make_float2(a.x + b.x, a.y - b.y);
  float2 dd = make_float2(a.x - b.x, a.y + b.y);
  float rev = (float)n * (1.0f / (float)NFFTC);
  float sn = hsin(rev), cs = hcos(rev);
  float2 xo = make_float2(0.5f*(cs*dd.x - sn*dd.y), 0.5f*(cs*dd.y + sn*dd.x));
  const float sc = 1.0f / (float)MH;
  return make_float2((0.5f*s.x - xo.y)*sc, (0.5f*s.y + xo.x)*sc);
}

// Fused: rfft split + band/harmonic multipliers + magnitude smoothing +
// inverse-rfft pack, for the pair (k, MH-k) per thread (natural writes).
// Blocks >= 4096 pack the conv weights (coalesced [mt][kt][quad][col]).
__global__ __launch_bounds__(256) void kspectral(const float2* __restrict__ Z,
    float2* __restrict__ A, const float* __restrict__ bwp,
    const float* __restrict__ fwp, const float* __restrict__ pm_in, SmultTab tab,
    const float* __restrict__ c1w, const float* __restrict__ c2w,
    const float* __restrict__ c3w, unsigned short* __restrict__ w1q,
    unsigned short* __restrict__ w2q, unsigned short* __restrict__ w3q) {
  const int bb = blockIdx.x;
  const int t = threadIdx.x;
  if (bb >= 4096) {                              // folded weight packing
    int i = (bb - 4096)*256 + t;
    if (i < 1024) {
      int e = i & 7, u4 = i >> 3;
      int col = u4 & 15, quad = (u4 >> 4) & 3, mi = u4 >> 6;
      float v = (quad == 0 && e < 5) ? c1w[(mi*16 + col)*5 + e] : 0.0f;
      w1q[i] = (unsigned short)rbf(v);
    }
    if (i < 10240) {
      int e = i & 7, u4 = i >> 3;
      int col = u4 & 15, quad = (u4 >> 4) & 3, mtkt = u4 >> 6;
      int kt = mtkt % 5, mt = mtkt / 5;
      int ch = mt*16 + col, c1 = quad*8 + e;
      w2q[i] = (unsigned short)rbf(c2w[ch*160 + c1*5 + kt]);
    }
    if (i < 40960) {
      int e = i & 7, u4 = i >> 3;
      int col = u4 & 15, quad = (u4 >> 4) & 3, mtkt = u4 >> 6;
      int kt = mtkt % 10, mt = mtkt / 10;
      int ch = mt*16 + col, c2 = (kt & 1)*32 + quad*8 + e;
      w3q[i] = (unsigned short)rbf(c3w[ch*320 + c2*5 + (kt >> 1)]);
    }
    return;
  }
  __shared__ float2 Xlo[258], Xhi[258];
  __shared__ float  Mlo[258], Mhi[258];
  const int k0 = bb * 256;
  const float pm1 = 1.0f + pm_in[0] * (1.0f/8388612.0f);   // 1 + sum/(L*4)
  for (int w = t; w < 258; w += 256) {
    int k = k0 - 1 + w;                          // in [-1, 1048576]
    float2 zk = Z[k & (MH-1)];
    float2 zm = Z[(MH - k) & (MH-1)];
    {
      float2 X = xsplit(zk, zm, (float)k * (1.0f/(float)NFFTC));
      float mv = 1.0f;
      if (k <= 38050) {
        const float blo[6] = {1.0f,4.0f,8.0f,13.0f,30.0f,100.0f};
        const float bhi[6] = {4.0f,8.0f,13.0f,30.0f,100.0f,200.0f};
        const float bcn[6] = {2.5f,6.0f,10.5f,21.5f,65.0f,150.0f};
        const float bhw[6] = {0.75f,1.0f,1.25f,4.25f,17.5f,25.0f};
        float f = (float)((double)k * (22050.0/4194304.0));
#pragma unroll
        for (int b = 0; b < 6; ++b) {
          if (f >= blo[b] && f <= bhi[b]) {
            float q = (f - bcn[b]) / bhw[b];
            float mask = expf(-0.5f*q*q);
            double frd = (double)k * ((double)bcn[b] / 22050.0);
            frd -= floor(frd);
            float tm = hsin((float)frd);
            mv *= (1.0f + mask * bwp[b] * (1.0f + 0.2f*tm));
          }
        }
      }
      if (k <= tab.maxe) {
        for (int ww = 0; ww < 40; ++ww) {
          int dlt = k - tab.hidx[ww];
          if (dlt >= -15 && dlt <= 15) {
            float x = (float)dlt * 0.2f;
            float win = expf(-0.5f*x*x);
            float enh = fwp[tab.fk[ww]] * win * tab.inv12[ww] * pm1;
            mv *= (1.0f + enh);
          }
        }
      }
      X.x *= mv; X.y *= mv;
      Xlo[w] = X; Mlo[w] = sqrtf(X.x*X.x + X.y*X.y);
    }
    {
      float2 X = xsplit(zm, zk, (float)(MH - k) * (1.0f/(float)NFFTC));
      Xhi[w] = X; Mhi[w] = sqrtf(X.x*X.x + X.y*X.y);
    }
  }
  __syncthreads();
  const int k = k0 + t, w = t + 1;
  float msl = (k == 0) ? Mlo[w] : 0.7f*Mlo[w] + 0.15f*(Mlo[w-1] + Mlo[w+1]);
  float2 xl = scale_xc(Xlo[w], Mlo[w], msl);
  float msh = (k == 0) ? Mhi[w] : 0.7f*Mhi[w] + 0.15f*(Mhi[w+1] + Mhi[w-1]);
  float2 xh = scale_xc(Xhi[w], Mhi[w], msh);
  A[k] = invpack(k, xl, xh);
  if (k >= 1) A[MH - k] = invpack(MH - k, xh, xl);
  if (bb == 4095 && t == 255) {                  // self-mirror bin n = MH/2
    float2 Xm = Xlo[257]; float Mm = Mlo[257];
    float ms = 0.7f*Mm + 0.15f*(Mlo[256] + Mhi[256]);
    float2 xm = scale_xc(Xm, Mm, ms);
    A[1048576] = invpack(1048576, xm, xm);
  }
}

// Fully-MFMA conv stack (R8 M-split version — best measured).
__global__ __launch_bounds__(256, 4) void kconv(const float* __restrict__ x,
    const unsigned short* __restrict__ w1q, const unsigned short* __restrict__ w2q,
    const unsigned short* __restrict__ w3q, const float* __restrict__ c1b,
    const float* __restrict__ c2b, const float* __restrict__ c3b,
    float* __restrict__ feat) {
  __shared__ float sb[552];
  __shared__ unsigned int sh1[4352];
  __shared__ unsigned int sh2[4224];
  const int tid  = threadIdx.x;
  const int blk  = blockIdx.x;
  const int s3   = blk * TO3;
  const int lane = tid & 63;
  const int wv   = tid >> 6;
  const int col  = lane & 15;
  const int quad = lane >> 4;

  const uint4* W1 = (const uint4*)w1q;             // idx = (mi*4+quad)*16+col
  AFrag a1w[2];
#pragma unroll
  for (int mi = 0; mi < 2; ++mi)
    a1w[mi].q = W1[(mi*4 + quad)*16 + col];

  const uint4* W2 = (const uint4*)w2q;             // idx = ((mt*5+kt)*4+quad)*16+col
  const int mt2 = (wv & 1) * 2;
  const int ntb2 = (wv >> 1) * 4;
  uint4 wk2[2][5];
#pragma unroll
  for (int mi = 0; mi < 2; ++mi)
#pragma unroll
    for (int kt = 0; kt < 5; ++kt)
      wk2[mi][kt] = W2[(((mt2+mi)*5 + kt)*4 + quad)*16 + col];

  float b1r[2][4], b2r[2][4];
#pragma unroll
  for (int mi = 0; mi < 2; ++mi)
#pragma unroll
    for (int r = 0; r < 4; ++r) {
      b1r[mi][r] = c1b[mi*16 + quad*4 + r];
      b2r[mi][r] = c2b[(mt2+mi)*16 + quad*4 + r];
    }

  {
    const int pb = 8*s3 - 14;
    for (int idx = tid; idx < 552; idx += 256) {
      int p = pb + idx;
      sb[idx] = (idx < 517 && p >= 0 && p < LSIG) ? x[p] : 0.0f;
    }
    if (tid < 128) sh2[4096 + tid] = 0u;
  }
  __syncthreads();

  // conv1 MFMA: 2 M-tiles x 17 N-tiles (positions 0..271, masked past 257).
  {
    const int a1 = 4*s3 - 6;
    for (int nt = wv; nt < 17; nt += 4) {
      const int n = nt*16 + col;
      BFrag bf;
      if (quad == 0) {
        const float* ps = &sb[2*n];
        bf.u[0] = pack_bf2(ps[0], ps[1]);
        bf.u[1] = pack_bf2(ps[2], ps[3]);
        bf.u[2] = pack_bf2(ps[4], ps[5]);
        bf.u[3] = pack_bf2(ps[6], ps[7]);
      } else {
        bf.u[0] = 0u; bf.u[1] = 0u; bf.u[2] = 0u; bf.u[3] = 0u;
      }
      f32x4v acc[2];
      acc[0] = (f32x4v){b1r[0][0], b1r[0][1], b1r[0][2], b1r[0][3]};
      acc[1] = (f32x4v){b1r[1][0], b1r[1][1], b1r[1][2], b1r[1][3]};
      acc[0] = __builtin_amdgcn_mfma_f32_16x16x32_bf16(a1w[0].s, bf.s, acc[0], 0, 0, 0);
      acc[1] = __builtin_amdgcn_mfma_f32_16x16x32_bf16(a1w[1].s, bf.s, acc[1], 0, 0, 0);
      const int o1 = a1 + n;
      const bool ok = (n <= 257) && (o1 >= 0) && (o1 < O1C);
#pragma unroll
      for (int mi = 0; mi < 2; ++mi) {
        float v0 = ok ? lrelu(acc[mi][0]) : 0.0f;
        float v1 = ok ? lrelu(acc[mi][1]) : 0.0f;
        float v2 = ok ? lrelu(acc[mi][2]) : 0.0f;
        float v3 = ok ? lrelu(acc[mi][3]) : 0.0f;
        uint2 pk; pk.x = pack_bf2(v0, v1); pk.y = pack_bf2(v2, v3);
        *(uint2*)&sh1[swz1(n, mi*8 + quad*2)] = pk;
      }
    }
  }
  __syncthreads();

  // conv2 MFMA: 2 mt x 4 nt, K-tiles 0..4 (tap-major); B-frag = one b128.
  f32x4v acc2[2][4];
#pragma unroll
  for (int mi = 0; mi < 2; ++mi)
#pragma unroll
    for (int nt = 0; nt < 4; ++nt)
      acc2[mi][nt] = (f32x4v){b2r[mi][0], b2r[mi][1], b2r[mi][2], b2r[mi][3]};
#pragma unroll
  for (int kt = 0; kt < 5; ++kt) {
#pragma unroll
    for (int nt = 0; nt < 4; ++nt) {
      const int n = (ntb2 + nt)*16 + col;
      const int row = 2*n + kt;
      BFrag bf;
      bf.q = *(const uint4*)&sh1[swz1(row, quad*4)];
      AFrag a0, a1; a0.q = wk2[0][kt]; a1.q = wk2[1][kt];
      acc2[0][nt] = __builtin_amdgcn_mfma_f32_16x16x32_bf16(a0.s, bf.s, acc2[0][nt], 0, 0, 0);
      acc2[1][nt] = __builtin_amdgcn_mfma_f32_16x16x32_bf16(a1.s, bf.s, acc2[1][nt], 0, 0, 0);
    }
  }

  // conv2 epilogue: lrelu + bounds -> h2t bf16 (b64 channel-quad writes)
  {
    const int a2 = 2*s3 - 2;
#pragma unroll
    for (int nt = 0; nt < 4; ++nt) {
      const int p = (ntb2 + nt)*16 + col;
      const int o2 = a2 + p;
      const bool ok = (o2 >= 0) && (o2 < O2C);
#pragma unroll
      for (int mi = 0; mi < 2; ++mi) {
        float v0 = ok ? lrelu(acc2[mi][nt][0]) : 0.0f;
        float v1 = ok ? lrelu(acc2[mi][nt][1]) : 0.0f;
        float v2 = ok ? lrelu(acc2[mi][nt][2]) : 0.0f;
        float v3 = ok ? lrelu(acc2[mi][nt][3]) : 0.0f;
        const int dwb = (mt2+mi)*8 + quad*2;
        uint2 pk; pk.x = pack_bf2(v0, v1); pk.y = pack_bf2(v2, v3);
        *(uint2*)&sh2[swz2(p, dwb)] = pk;
      }
    }
  }
  __syncthreads();

  // conv3 MFMA: TWO passes of 1 M-tile x 4 N-tiles x 10 K-tiles (tap-major).
  {
    const uint4* W3 = (const uint4*)w3q;           // idx = ((mt*10+kt)*4+quad)*16+col
    const int slot = (blk & 255) * 128;
#pragma unroll
    for (int pass = 0; pass < 2; ++pass) {
      const int mt = wv + 4*pass;
      uint4 wk3[10];
#pragma unroll
      for (int kt = 0; kt < 10; ++kt)
        wk3[kt] = W3[((mt*10 + kt)*4 + quad)*16 + col];
      float b3r[4];
#pragma unroll
      for (int r = 0; r < 4; ++r) b3r[r] = c3b[mt*16 + quad*4 + r];
      f32x4v acc3[4];
#pragma unroll
      for (int nt = 0; nt < 4; ++nt)
        acc3[nt] = (f32x4v){b3r[0], b3r[1], b3r[2], b3r[3]};
#pragma unroll
      for (int kt = 0; kt < 10; ++kt) {
        const int tap = kt >> 1;
        const int hh  = (kt & 1) * 16;
#pragma unroll
        for (int nt = 0; nt < 4; ++nt) {
          const int n = nt*16 + col;
          const int row = 2*n + tap;
          BFrag bf;
          bf.q = *(const uint4*)&sh2[swz2(row, hh + quad*4)];
          AFrag a; a.q = wk3[kt];
          acc3[nt] = __builtin_amdgcn_mfma_f32_16x16x32_bf16(a.s, bf.s, acc3[nt], 0, 0, 0);
        }
      }
#pragma unroll
      for (int r = 0; r < 4; ++r) {
        const int ch = mt*16 + quad*4 + r;
        float v = 0.0f;
#pragma unroll
        for (int nt = 0; nt < 4; ++nt) {
          const int n = nt*16 + col;
          const bool ok = (n < TO3) && (s3 + n < O3C);
          if (ok) v += lrelu(acc3[nt][r]);
        }
        v += __shfl_xor(v, 1);
        v += __shfl_xor(v, 2);
        v += __shfl_xor(v, 4);
        v += __shfl_xor(v, 8);
        if (col == 0) atomicAdd(&feat[slot + ch], v);
      }
    }
  }
}

// final mean + 2-layer MLP -> one f32 scalar
__global__ __launch_bounds__(256) void kfinal(const float* __restrict__ feat,
    const float* __restrict__ mw1, const float* __restrict__ mb1,
    const float* __restrict__ mw2, const float* __restrict__ mb2,
    float* __restrict__ out) {
  __shared__ float sfeat[128];
  __shared__ float red[256];
  const int tid = threadIdx.x;
  if (tid < 128) {
    float s = 0.0f;
    for (int sl = 0; sl < 256; ++sl) s += feat[sl*128 + tid];
    sfeat[tid] = s / 262145.0f;
  }
  __syncthreads();
  float y = mb1[tid];
  for (int i = 0; i < 128; ++i) y += sfeat[i] * mw1[i*256 + tid];
  y = y > 0.0f ? y : 0.2f*y;
  red[tid] = y * mw2[tid];
  __syncthreads();
  for (int off = 128; off > 0; off >>= 1) {
    if (tid < off) red[tid] += red[tid+off];
    __syncthreads();
  }
  if (tid == 0) out[0] = red[0] + mb2[0];
}

extern "C" void kernel_launch(void* const* d_in, const int* in_sizes, int n_in,
                              void* d_out, int out_size, void* d_ws, size_t ws_size,
                              hipStream_t stream) {
  (void)in_sizes; (void)n_in; (void)out_size; (void)ws_size;
  const float* z   = (const float*)d_in[0];
  const float* bw  = (const float*)d_in[2];
  const float* fw  = (const float*)d_in[3];
  const float* hp  = (const float*)d_in[4];
  const float* tw1 = (const float*)d_in[5];
  const float* tb1 = (const float*)d_in[6];
  const float* tw2 = (const float*)d_in[7];
  const float* tb2 = (const float*)d_in[8];
  const float* tw3 = (const float*)d_in[9];
  const float* tb3 = (const float*)d_in[10];
  const float* c1w = (const float*)d_in[11];
  const float* c1b = (const float*)d_in[12];
  const float* c2w = (const float*)d_in[13];
  const float* c2b = (const float*)d_in[14];
  const float* c3w = (const float*)d_in[15];
  const float* c3b = (const float*)d_in[16];
  const float* mw1 = (const float*)d_in[17];
  const float* mb1 = (const float*)d_in[18];
  const float* mw2 = (const float*)d_in[19];
  const float* mb2 = (const float*)d_in[20];

  char* wsb = (char*)d_ws;
  float2* A    = (float2*)(wsb + A_OFF);
  float2* B    = (float2*)(wsb + B_OFF);
  float*  PM   = (float*)(wsb + PM_OFF);
  float*  FEAT = (float*)(wsb + FEAT_OFF);
  unsigned short* W1Q = (unsigned short*)(wsb + W1Q_OFF);
  unsigned short* W2Q = (unsigned short*)(wsb + W2Q_OFF);
  unsigned short* W3Q = (unsigned short*)(wsb + W3Q_OFF);

  // static harmonic-window table
  SmultTab tab;
  {
    const double spec[8] = {7.83, 528.0, 396.0, 2.5, 14.1, 432.0, 6.0, 30.0};
    int n = 0, maxe = 0;
    for (int kk = 0; kk < 8; ++kk)
      for (int m = 1; m <= 5; ++m) {
        double hf = spec[kk] * (double)m;
        if (hf >= 11025.0) continue;
        int hidx = (int)std::floor(hf * (4194304.0/22050.0) + 0.5);
        tab.hidx[n]  = hidx;
        tab.inv12[n] = (float)(1.0/std::pow((double)m, 1.2));
        tab.fk[n]    = kk;
        if (hidx + 15 > maxe) maxe = hidx + 15;
        ++n;
      }
    tab.maxe = maxe;  // n == 40
  }

  (void)hipMemsetAsync(wsb + PM_OFF, 0, 4, stream);   // PM only

  // fused: forward FFT pass 1 (blocks 0..511) + prog_mean + FEAT zero
  kfirst<<<1536,512,0,stream>>>(z, A, tw1,tb1,tw2,tb2,tw3,tb3,hp, PM, FEAT);

  // forward cfft: radix 128 x 128 x 128 -> natural-order spectrum in A
  kfft128<true,false><<<512,512,0,stream>>>(A, B, 128);
  kfft128<true,false><<<512,512,0,stream>>>(B, A, 16384);

  // fused spectral stage (natural writes) + weight packing
  kspectral<<<4256,256,0,stream>>>(A, B, bw, fw, PM, tab, c1w, c2w, c3w, W1Q, W2Q, W3Q);

  // inverse cfft: radix 128 x 128 x 128 (last pass truncated to needed bins)
  kfft128<false,false><<<512,512,0,stream>>>(B, A, 1);
  kfft128<false,false><<<512,512,0,stream>>>(A, B, 128);
  kfft128<false,true ><<<512,512,0,stream>>>(B, A, 16384);

  kconv<<<NB3,256,0,stream>>>((const float*)A, W1Q, W2Q, W3Q, c1b, c2b, c3b, FEAT);
  kfinal<<<1,256,0,stream>>>(FEAT, mw1, mb1, mw2, mb2, (float*)d_out);
}